// Round 14
// baseline (147.314 us; speedup 1.0000x reference)
//
#include <hip/hip_runtime.h>

typedef __attribute__((ext_vector_type(8))) short bf16x8;
typedef __attribute__((ext_vector_type(4))) float f32x4;
typedef __attribute__((ext_vector_type(2))) float pk2;

// Problem constants (from reference)
constexpr int B    = 8;
constexpr int N    = 4096;
constexpr int FIN  = 128;
constexpr int NT   = B * N;        // 32768
constexpr int H    = 4;
constexpr int C    = 64;
constexpr int D1   = H * C;        // 256
constexpr int E    = 524288;
constexpr int EPB  = E / B;        // 65536 main edges per graph (graph-sorted)
constexpr int NSLOT = 18;          // per-kt B slots: 0..16 = bh(nt0..16), 17 = blAtt(nt16)
constexpr int CAP  = 64;           // adjacency bucket capacity (max deg ~40, pad <= 63)

// bf16 round-to-nearest-even helpers
__device__ __forceinline__ unsigned short f2bf(float f) {
    unsigned u = __float_as_uint(f);
    return (unsigned short)((u + 0x7FFFu + ((u >> 16) & 1u)) >> 16);
}
__device__ __forceinline__ float bf2f(unsigned short b) {
    return __uint_as_float(((unsigned)b) << 16);
}

// ---- pack one layer's Bext = [W | Ws | Wd | 0] into per-kt slot layout ----
__device__ __forceinline__ void pack_body(
    const float* __restrict__ W, const float* __restrict__ as_,
    const float* __restrict__ ad_, unsigned short* __restrict__ pB, int g)
{
    int kt  = g / (NSLOT * 64);
    int rem = g % (NSLOT * 64);
    int slot = rem >> 6, l = rem & 63;
    int k0 = kt * 32 + 8 * (l >> 4);
    bool wantLo = (slot == 17);
    int nt = wantLo ? 16 : slot;
    int n  = nt * 16 + (l & 15);
    bf16x8 o;
    #pragma unroll
    for (int j = 0; j < 8; ++j) {
        int k = k0 + j;
        float v;
        if (n < 256) {
            v = W[k * D1 + n];
        } else if (n < 264) {
            int idx = n - 256, hh = idx & 3;
            const float* av = (idx < 4) ? as_ : ad_;
            float s = 0.f;
            #pragma unroll 8
            for (int c = 0; c < C; ++c) s += W[k * D1 + hh * C + c] * av[hh * C + c];
            v = s;
        } else {
            v = 0.f;
        }
        unsigned short hb = f2bf(v);
        o[j] = wantLo ? (short)f2bf(v - bf2f(hb)) : (short)hb;
    }
    *reinterpret_cast<bf16x8*>(pB + (size_t)g * 8) = o;
}

// ---- fused: LDS-counting adjacency build (bid<8, one block per graph) |
//      pack B1/B2 + sentinels (bid in [8,62)) | x0 + split (bid>=62) ----
__global__ __launch_bounds__(256) void k_combo(
    const float* __restrict__ x, const int* __restrict__ ei,
    unsigned short* __restrict__ hi, unsigned short* __restrict__ lo,
    float* __restrict__ out, unsigned* __restrict__ cnt, int* __restrict__ slots,
    const float* __restrict__ W1, const float* __restrict__ as1, const float* __restrict__ ad1,
    const float* __restrict__ W2, const float* __restrict__ as2, const float* __restrict__ ad2,
    unsigned short* __restrict__ pB1, unsigned short* __restrict__ pB2,
    float* __restrict__ asrc, unsigned short* __restrict__ xpb)
{
    __shared__ unsigned lcnt[N];              // 16 KB: per-graph degree counters
    int bid = blockIdx.x, t = threadIdx.x;

    if (bid < 8) {
        // ---- adjacency build for graph g = bid, entirely via LDS atomics ----
        int g = bid;
        // self-loops initialize: lcnt = 1, slot0 = self (no atomics needed)
        for (int i = t; i < N; i += 256) {
            lcnt[i] = 1u;
            int node = (g << 12) + i;
            slots[(size_t)node * CAP] = node * 4;
        }
        __syncthreads();
        const int* srcp = ei + (size_t)g * EPB;
        const int* dstp = ei + E + (size_t)g * EPB;
        // main edges: 4 independent per thread per iteration (MLP)
        for (int base = 0; base < EPB; base += 1024) {
            int i0 = base + t;
            int s0 = srcp[i0], d0 = dstp[i0];
            int s1 = srcp[i0 + 256], d1 = dstp[i0 + 256];
            int s2 = srcp[i0 + 512], d2 = dstp[i0 + 512];
            int s3 = srcp[i0 + 768], d3 = dstp[i0 + 768];
            unsigned p0 = atomicAdd(&lcnt[d0 & (N - 1)], 1u);
            unsigned p1 = atomicAdd(&lcnt[d1 & (N - 1)], 1u);
            unsigned p2 = atomicAdd(&lcnt[d2 & (N - 1)], 1u);
            unsigned p3 = atomicAdd(&lcnt[d3 & (N - 1)], 1u);
            slots[(size_t)d0 * CAP + p0] = s0 * 4;
            slots[(size_t)d1 * CAP + p1] = s1 * 4;
            slots[(size_t)d2 * CAP + p2] = s2 * 4;
            slots[(size_t)d3 * CAP + p3] = s3 * 4;
        }
        __syncthreads();
        for (int i = t; i < N; i += 256) cnt[(g << 12) + i] = lcnt[i];
        return;
    }

    if (bid < 62) {  // pack blocks + sentinels
        int pb = bid - 8;
        if (pb == 0) {
            if (t < 4)  asrc[NT * H + t] = -1e30f;
            if (t < 64) reinterpret_cast<uint2*>(xpb)[(size_t)NT * 64 + t] = make_uint2(0u, 0u);
        }
        if (pb < 18) pack_body(W1, as1, ad1, pB1, pb * 256 + t);
        else         pack_body(W2, as2, ad2, pB2, (pb - 18) * 256 + t);
        return;
    }

    // ---- x0 + split for 8 nodes of graph g (XCD-pinned) ----
    int nb = bid - 62;                        // 0..4095
    int g  = nb & 7, loc = nb >> 3;
    int node = (g << 12) + (loc << 3) + (t >> 5);
    int q = t & 31;
    float4 v = reinterpret_cast<const float4*>(x)[node * 32 + q];
    ushort4 h, l;
    h.x = f2bf(v.x); l.x = f2bf(v.x - bf2f(h.x));
    h.y = f2bf(v.y); l.y = f2bf(v.y - bf2f(h.y));
    h.z = f2bf(v.z); l.z = f2bf(v.z - bf2f(h.z));
    h.w = f2bf(v.w); l.w = f2bf(v.w - bf2f(h.w));
    reinterpret_cast<ushort4*>(hi)[node * 32 + q] = h;
    reinterpret_cast<ushort4*>(lo)[node * 32 + q] = l;
    float s = v.x + v.y + v.z + v.w;
    #pragma unroll
    for (int o = 16; o; o >>= 1) s += __shfl_xor(s, o);
    if (q == 0) {
        int n = node & (N - 1);
        out[g * (3 * N) + n] = s * (1.0f / 128.0f);
    }
}

// ---- MFMA GEMM: C[NT x 264] = A[NT x K] * Bext, software-pipelined, XCD-pinned.
//      BM=64; 4 waves = 2 wm x 2 wn; wave: 2 m-tiles x 9 slots. ----
template <int K, bool PAD>
__global__ __launch_bounds__(256) void k_mfma(
    const unsigned short* __restrict__ Ahi, const unsigned short* __restrict__ Alo,
    const unsigned short* __restrict__ pB,
    unsigned short* __restrict__ xpb, float* __restrict__ asrc, float* __restrict__ adst,
    const unsigned* __restrict__ cnt, int* __restrict__ slots)
{
    constexpr int KT = K / 32;
    int t = threadIdx.x, lane = t & 63, w = t >> 6;

    if (PAD && blockIdx.x >= NT / 64) {   // bucket padding blocks (XCD-pinned)
        int bl = blockIdx.x - NT / 64;    // 128 blocks: 16/graph
        int node = ((bl & 7) << 12) + ((bl >> 3) << 8) + t;
        int deg = (int)cnt[node];
        int dpad = ((deg + 1) & ~1) + 14;  // covers 3-pair lookahead overshoot
        int* sl = slots + (size_t)node * CAP;
        for (int i = deg; i < dpad; ++i) sl[i] = NT * 4;
        return;
    }

    int wm = w & 1, wn = w >> 1;
    // graph (bid&7) -> XCD (bid&7): rows of graph g computed on XCD g
    int m0 = ((blockIdx.x & 7) << 12) + ((blockIdx.x >> 3) << 6) + wm * 32;
    int sBase = wn * 9;

    f32x4 acc[2][9];
    #pragma unroll
    for (int i = 0; i < 2; ++i)
        #pragma unroll
        for (int j = 0; j < 9; ++j)
            acc[i][j] = (f32x4){0.f, 0.f, 0.f, 0.f};

    int aRow = m0 + (lane & 15);
    int aCol = 8 * (lane >> 4);
    const unsigned short* a0h = Ahi + (size_t)aRow * K + aCol;
    const unsigned short* a0l = Alo + (size_t)aRow * K + aCol;
    const unsigned short* bp  = pB + ((size_t)sBase * 64 + lane) * 8;

    bf16x8 bc[9], bn[9];
    bf16x8 ah0c, al0c, ah1c, al1c, ah0n, al0n, ah1n, al1n;

    #pragma unroll
    for (int j = 0; j < 9; ++j) bc[j] = *reinterpret_cast<const bf16x8*>(bp + j * 512);
    ah0c = *reinterpret_cast<const bf16x8*>(a0h);
    al0c = *reinterpret_cast<const bf16x8*>(a0l);
    ah1c = *reinterpret_cast<const bf16x8*>(a0h + 16 * K);
    al1c = *reinterpret_cast<const bf16x8*>(a0l + 16 * K);

    #pragma unroll
    for (int kt = 0; kt < KT; ++kt) {
        if (kt + 1 < KT) {
            const unsigned short* bpn = bp + (size_t)(kt + 1) * NSLOT * 64 * 8;
            #pragma unroll
            for (int j = 0; j < 9; ++j) bn[j] = *reinterpret_cast<const bf16x8*>(bpn + j * 512);
            ah0n = *reinterpret_cast<const bf16x8*>(a0h + (kt + 1) * 32);
            al0n = *reinterpret_cast<const bf16x8*>(a0l + (kt + 1) * 32);
            ah1n = *reinterpret_cast<const bf16x8*>(a0h + 16 * K + (kt + 1) * 32);
            al1n = *reinterpret_cast<const bf16x8*>(a0l + 16 * K + (kt + 1) * 32);
        }
        __builtin_amdgcn_sched_barrier(0);   // keep prefetch loads ahead of MFMAs
        if (wn == 0) {
            #pragma unroll
            for (int j = 0; j < 9; ++j) {
                acc[0][j] = __builtin_amdgcn_mfma_f32_16x16x32_bf16(ah0c, bc[j], acc[0][j], 0, 0, 0);
                acc[1][j] = __builtin_amdgcn_mfma_f32_16x16x32_bf16(ah1c, bc[j], acc[1][j], 0, 0, 0);
                acc[0][j] = __builtin_amdgcn_mfma_f32_16x16x32_bf16(al0c, bc[j], acc[0][j], 0, 0, 0);
                acc[1][j] = __builtin_amdgcn_mfma_f32_16x16x32_bf16(al1c, bc[j], acc[1][j], 0, 0, 0);
            }
        } else {
            #pragma unroll
            for (int j = 0; j < 8; ++j) {
                acc[0][j] = __builtin_amdgcn_mfma_f32_16x16x32_bf16(ah0c, bc[j], acc[0][j], 0, 0, 0);
                acc[1][j] = __builtin_amdgcn_mfma_f32_16x16x32_bf16(ah1c, bc[j], acc[1][j], 0, 0, 0);
                acc[0][j] = __builtin_amdgcn_mfma_f32_16x16x32_bf16(al0c, bc[j], acc[0][j], 0, 0, 0);
                acc[1][j] = __builtin_amdgcn_mfma_f32_16x16x32_bf16(al1c, bc[j], acc[1][j], 0, 0, 0);
            }
            acc[0][7] = __builtin_amdgcn_mfma_f32_16x16x32_bf16(ah0c, bc[8], acc[0][7], 0, 0, 0);
            acc[1][7] = __builtin_amdgcn_mfma_f32_16x16x32_bf16(ah1c, bc[8], acc[1][7], 0, 0, 0);
        }
        if (kt + 1 < KT) {
            #pragma unroll
            for (int j = 0; j < 9; ++j) bc[j] = bn[j];
            ah0c = ah0n; al0c = al0n; ah1c = ah1n; al1c = al1n;
        }
    }

    // epilogue: C layout col = lane&15, row = (lane>>4)*4 + r  [m89-verified]
    #pragma unroll
    for (int mt = 0; mt < 2; ++mt) {
        int rowB = m0 + mt * 16 + (lane >> 4) * 4;
        if (wn == 0) {
            #pragma unroll
            for (int j = 0; j < 9; ++j) {
                int col = j * 16 + (lane & 15);
                #pragma unroll
                for (int r = 0; r < 4; ++r)
                    xpb[(size_t)(rowB + r) * D1 + col] = f2bf(acc[mt][j][r]);
            }
        } else {
            #pragma unroll
            for (int j = 0; j < 8; ++j) {
                int nt = 9 + j;
                int col = nt * 16 + (lane & 15);
                #pragma unroll
                for (int r = 0; r < 4; ++r) {
                    int row = rowB + r;
                    float v = acc[mt][j][r];
                    if (col < 256)      xpb[(size_t)row * D1 + col] = f2bf(v);
                    else if (col < 260) asrc[row * H + (col - 256)] = v;
                    else if (col < 264) adst[row * H + (col - 260)] = v;
                }
            }
        }
    }
}

// ---- node aggregation: one wave per node; half-wave per edge (2 edges/step);
//      packed-f32 FMA + 3-slot circular prefetch (6 edges in flight) ----
__global__ __launch_bounds__(256) void k_node(
    const unsigned* __restrict__ cnt, const int* __restrict__ slots,
    const float* __restrict__ asrc, const float* __restrict__ adst,
    const unsigned short* __restrict__ xp,   // bf16 [NT+1][256]
    const float* __restrict__ bias, const float* __restrict__ pw,
    const float* __restrict__ pb,
    unsigned short* __restrict__ hhi, unsigned short* __restrict__ hlo,
    float* __restrict__ out, int sec)
{
    int bid = blockIdx.x;
    int w = threadIdx.x >> 6, lane = threadIdx.x & 63;
    int half = lane >> 5;                     // which edge of the pair
    int hl   = lane & 31;                     // lane within half: ch 8*hl..8*hl+7
    int head = hl >> 3;                       // 8 lanes per head
    // graph g = bid&7 pinned to XCD g; 4 nodes per block (one per wave)
    int node = ((bid & 7) << 12) | (((bid >> 3) << 2) + w);

    int deg = (int)cnt[node];                 // >= 1 (self loop)
    int dp  = (deg + 1) & ~1;                 // pair-rounded; overshoot hits sentinels
    const int* sl = slots + (size_t)node * CAP;
    float adh = adst[node * H + head];
    const uint4* xp4 = (const uint4*)xp;      // 8 bf16 per lane

    float den = 0.f;
    pk2 acc01 = {0.f, 0.f}, acc23 = {0.f, 0.f}, acc45 = {0.f, 0.f}, acc67 = {0.f, 0.f};

    #define PROC(aa, vv)                                                     \
    {                                                                        \
        float l  = aa + adh;                                                 \
        float ev = __expf(fmaxf(l, 0.2f * l));                               \
        den += ev;                                                           \
        pk2 e2 = {ev, ev};                                                   \
        pk2 t01 = {__uint_as_float(vv.x << 16), __uint_as_float(vv.x & 0xFFFF0000u)}; \
        pk2 t23 = {__uint_as_float(vv.y << 16), __uint_as_float(vv.y & 0xFFFF0000u)}; \
        pk2 t45 = {__uint_as_float(vv.z << 16), __uint_as_float(vv.z & 0xFFFF0000u)}; \
        pk2 t67 = {__uint_as_float(vv.w << 16), __uint_as_float(vv.w & 0xFFFF0000u)}; \
        acc01 = __builtin_elementwise_fma(e2, t01, acc01);                   \
        acc23 = __builtin_elementwise_fma(e2, t23, acc23);                   \
        acc45 = __builtin_elementwise_fma(e2, t45, acc45);                   \
        acc67 = __builtin_elementwise_fma(e2, t67, acc67);                   \
    }

    // 3-slot circular prefetch: pairs 0,2,4 preloaded; prefetch i+6 before use
    int   s_;
    float aX, aY, aZ, a_;
    uint4 vX, vY, vZ, v_;
    s_ = sl[0 + half]; aX = asrc[s_ + head]; vX = xp4[(s_ << 3) + hl];
    s_ = sl[2 + half]; aY = asrc[s_ + head]; vY = xp4[(s_ << 3) + hl];
    s_ = sl[4 + half]; aZ = asrc[s_ + head]; vZ = xp4[(s_ << 3) + hl];

    for (int i = 0; i < dp; i += 6) {
        s_ = sl[i + 6 + half];  a_ = asrc[s_ + head]; v_ = xp4[(s_ << 3) + hl];
        PROC(aX, vX); aX = a_; vX = v_;
        s_ = sl[i + 8 + half];  a_ = asrc[s_ + head]; v_ = xp4[(s_ << 3) + hl];
        PROC(aY, vY); aY = a_; vY = v_;
        s_ = sl[i + 10 + half]; a_ = asrc[s_ + head]; v_ = xp4[(s_ << 3) + hl];
        PROC(aZ, vZ); aZ = a_; vZ = v_;
    }
    #undef PROC

    // combine the two halves (lane l <-> l^32 hold same channels, different edges)
    den      += __shfl_xor(den, 32);
    acc01[0] += __shfl_xor(acc01[0], 32);
    acc01[1] += __shfl_xor(acc01[1], 32);
    acc23[0] += __shfl_xor(acc23[0], 32);
    acc23[1] += __shfl_xor(acc23[1], 32);
    acc45[0] += __shfl_xor(acc45[0], 32);
    acc45[1] += __shfl_xor(acc45[1], 32);
    acc67[0] += __shfl_xor(acc67[0], 32);
    acc67[1] += __shfl_xor(acc67[1], 32);

    float invd = 1.f / (den + 1e-16f);
    float4 b0 = reinterpret_cast<const float4*>(bias)[hl * 2];
    float4 b1 = reinterpret_cast<const float4*>(bias)[hl * 2 + 1];
    float4 p0 = reinterpret_cast<const float4*>(pw)[hl * 2];
    float4 p1 = reinterpret_cast<const float4*>(pw)[hl * 2 + 1];

    float h0 = fmaf(acc01[0], invd, b0.x), h1 = fmaf(acc01[1], invd, b0.y),
          h2 = fmaf(acc23[0], invd, b0.z), h3 = fmaf(acc23[1], invd, b0.w),
          h4 = fmaf(acc45[0], invd, b1.x), h5 = fmaf(acc45[1], invd, b1.y),
          h6 = fmaf(acc67[0], invd, b1.z), h7 = fmaf(acc67[1], invd, b1.w);
    h0 = h0 > 0.f ? h0 : __expf(h0) - 1.f;
    h1 = h1 > 0.f ? h1 : __expf(h1) - 1.f;
    h2 = h2 > 0.f ? h2 : __expf(h2) - 1.f;
    h3 = h3 > 0.f ? h3 : __expf(h3) - 1.f;
    h4 = h4 > 0.f ? h4 : __expf(h4) - 1.f;
    h5 = h5 > 0.f ? h5 : __expf(h5) - 1.f;
    h6 = h6 > 0.f ? h6 : __expf(h6) - 1.f;
    h7 = h7 > 0.f ? h7 : __expf(h7) - 1.f;

    if (hhi && half == 0) {
        unsigned short q0 = f2bf(h0), q1 = f2bf(h1), q2 = f2bf(h2), q3 = f2bf(h3),
                       q4 = f2bf(h4), q5 = f2bf(h5), q6 = f2bf(h6), q7 = f2bf(h7);
        uint4 hw, lw;
        hw.x = (unsigned)q0 | ((unsigned)q1 << 16);
        hw.y = (unsigned)q2 | ((unsigned)q3 << 16);
        hw.z = (unsigned)q4 | ((unsigned)q5 << 16);
        hw.w = (unsigned)q6 | ((unsigned)q7 << 16);
        lw.x = (unsigned)f2bf(h0 - bf2f(q0)) | ((unsigned)f2bf(h1 - bf2f(q1)) << 16);
        lw.y = (unsigned)f2bf(h2 - bf2f(q2)) | ((unsigned)f2bf(h3 - bf2f(q3)) << 16);
        lw.z = (unsigned)f2bf(h4 - bf2f(q4)) | ((unsigned)f2bf(h5 - bf2f(q5)) << 16);
        lw.w = (unsigned)f2bf(h6 - bf2f(q6)) | ((unsigned)f2bf(h7 - bf2f(q7)) << 16);
        reinterpret_cast<uint4*>(hhi)[node * 32 + hl] = hw;
        reinterpret_cast<uint4*>(hlo)[node * 32 + hl] = lw;
    }

    float p = h0 * p0.x + h1 * p0.y + h2 * p0.z + h3 * p0.w
            + h4 * p1.x + h5 * p1.y + h6 * p1.z + h7 * p1.w;
    #pragma unroll
    for (int o = 16; o; o >>= 1) p += __shfl_xor(p, o);
    if (lane == 0) {
        int b = node >> 12;
        int n = node & (N - 1);
        out[b * (3 * N) + sec * N + n] = p + pb[0];
    }
}

extern "C" void kernel_launch(void* const* d_in, const int* in_sizes, int n_in,
                              void* d_out, int out_size, void* d_ws, size_t ws_size,
                              hipStream_t stream) {
    const float* x   = (const float*)d_in[0];
    const int*   ei  = (const int*)d_in[1];
    const float* W1  = (const float*)d_in[2];
    const float* as1 = (const float*)d_in[3];
    const float* ad1 = (const float*)d_in[4];
    const float* b1  = (const float*)d_in[5];
    const float* W2  = (const float*)d_in[6];
    const float* as2 = (const float*)d_in[7];
    const float* ad2 = (const float*)d_in[8];
    const float* b2  = (const float*)d_in[9];
    const float* pw1 = (const float*)d_in[10];
    const float* pb1 = (const float*)d_in[11];
    const float* pw2 = (const float*)d_in[12];
    const float* pb2 = (const float*)d_in[13];
    float* out = (float*)d_out;

    // workspace layout (16B aligned blocks); xpb/asrc have +1 sentinel row
    unsigned short* xpb  = (unsigned short*)d_ws;             // (NT+1)*D1 bf16
    unsigned short* xhi  = xpb  + (size_t)(NT + 1) * D1;      // NT*FIN
    unsigned short* xlo  = xhi  + (size_t)NT * FIN;           // NT*FIN
    unsigned short* h1hi = xlo  + (size_t)NT * FIN;           // NT*D1
    unsigned short* h1lo = h1hi + (size_t)NT * D1;            // NT*D1
    float*    asrc   = (float*)(h1lo + (size_t)NT * D1);      // (NT+1)*H
    float*    adst   = asrc + (size_t)(NT + 1) * H;           // NT*H
    unsigned short* pB1 = (unsigned short*)(adst + (size_t)NT * H); // 4*18*64*8
    unsigned short* pB2 = pB1 + (size_t)4 * NSLOT * 64 * 8;         // 8*18*64*8
    unsigned* cnt    = (unsigned*)(pB2 + (size_t)8 * NSLOT * 64 * 8); // NT
    int*      slots  = (int*)(cnt + NT);                      // NT*CAP

    // 5 dispatches total (LDS-counting build; no k_zero, no global atomics)
    k_combo<<<62 + NT / 8, 256, 0, stream>>>(x, ei, xhi, xlo, out, cnt, slots,
                                             W1, as1, ad1, W2, as2, ad2, pB1, pB2,
                                             asrc, xpb);

    // ---------------- layer 1 (K = 128) ----------------
    k_mfma<128, true><<<NT / 64 + NT / 256, 256, 0, stream>>>(
        xhi, xlo, pB1, xpb, asrc, adst, cnt, slots);
    k_node<<<NT / 4, 256, 0, stream>>>(cnt, slots, asrc, adst, xpb,
                                       b1, pw1, pb1, h1hi, h1lo, out, 1);

    // ---------------- layer 2 (K = 256) ----------------
    k_mfma<256, false><<<NT / 64, 256, 0, stream>>>(
        h1hi, h1lo, pB2, xpb, asrc, adst, cnt, slots);
    k_node<<<NT / 4, 256, 0, stream>>>(cnt, slots, asrc, adst, xpb,
                                       b2, pw2, pb2, nullptr, nullptr, out, 2);
}

// Round 15
// 115.895 us; speedup vs baseline: 1.2711x; 1.2711x over previous
//
#include <hip/hip_runtime.h>

typedef __attribute__((ext_vector_type(8))) short bf16x8;
typedef __attribute__((ext_vector_type(4))) float f32x4;
typedef __attribute__((ext_vector_type(2))) float pk2;

// Problem constants (from reference)
constexpr int B    = 8;
constexpr int N    = 4096;
constexpr int FIN  = 128;
constexpr int NT   = B * N;        // 32768
constexpr int H    = 4;
constexpr int C    = 64;
constexpr int D1   = H * C;        // 256
constexpr int E    = 524288;
constexpr int EPB  = E / B;        // 65536 main edges per graph (graph-sorted)
constexpr int CHK  = 8192;         // edges per phase-A chunk (8 chunks/graph)
constexpr int NSLOT = 18;          // per-kt B slots: 0..16 = bh(nt0..16), 17 = blAtt(nt16)
constexpr int CAP  = 64;           // adjacency bucket capacity (max deg ~40, pad <= 63)

// bf16 round-to-nearest-even helpers
__device__ __forceinline__ unsigned short f2bf(float f) {
    unsigned u = __float_as_uint(f);
    return (unsigned short)((u + 0x7FFFu + ((u >> 16) & 1u)) >> 16);
}
__device__ __forceinline__ float bf2f(unsigned short b) {
    return __uint_as_float(((unsigned)b) << 16);
}

// ---- pack one layer's Bext = [W | Ws | Wd | 0] into per-kt slot layout ----
__device__ __forceinline__ void pack_body(
    const float* __restrict__ W, const float* __restrict__ as_,
    const float* __restrict__ ad_, unsigned short* __restrict__ pB, int g)
{
    int kt  = g / (NSLOT * 64);
    int rem = g % (NSLOT * 64);
    int slot = rem >> 6, l = rem & 63;
    int k0 = kt * 32 + 8 * (l >> 4);
    bool wantLo = (slot == 17);
    int nt = wantLo ? 16 : slot;
    int n  = nt * 16 + (l & 15);
    bf16x8 o;
    #pragma unroll
    for (int j = 0; j < 8; ++j) {
        int k = k0 + j;
        float v;
        if (n < 256) {
            v = W[k * D1 + n];
        } else if (n < 264) {
            int idx = n - 256, hh = idx & 3;
            const float* av = (idx < 4) ? as_ : ad_;
            float s = 0.f;
            #pragma unroll 8
            for (int c = 0; c < C; ++c) s += W[k * D1 + hh * C + c] * av[hh * C + c];
            v = s;
        } else {
            v = 0.f;
        }
        unsigned short hb = f2bf(v);
        o[j] = wantLo ? (short)f2bf(v - bf2f(hb)) : (short)hb;
    }
    *reinterpret_cast<bf16x8*>(pB + (size_t)g * 8) = o;
}

// ---- fused: phase-A rank-capture histogram (bid<64) | pack+sentinels (64..117)
//      | x0 + split (bid>=118, XCD-pinned via g = bid&7) ----
__global__ __launch_bounds__(256) void k_combo(
    const float* __restrict__ x, const int* __restrict__ ei,
    unsigned short* __restrict__ hi, unsigned short* __restrict__ lo,
    float* __restrict__ out,
    unsigned short* __restrict__ pos, unsigned short* __restrict__ bcnt,
    const float* __restrict__ W1, const float* __restrict__ as1, const float* __restrict__ ad1,
    const float* __restrict__ W2, const float* __restrict__ as2, const float* __restrict__ ad2,
    unsigned short* __restrict__ pB1, unsigned short* __restrict__ pB2,
    float* __restrict__ asrc, unsigned short* __restrict__ xpb)
{
    __shared__ unsigned lcnt[N];              // 16 KB (phase-A blocks only)
    int bid = blockIdx.x, t = threadIdx.x;

    if (bid < 64) {
        // ---- phase A: graph g, chunk c; LDS histogram + per-edge local rank ----
        int g = bid & 7, c = bid >> 3;        // block -> XCD g
        for (int i = t; i < N; i += 256) lcnt[i] = 0u;
        __syncthreads();
        const int* dstp = ei + E + (size_t)g * EPB + (size_t)c * CHK;
        unsigned short* posp = pos + (size_t)g * EPB + (size_t)c * CHK;
        for (int base = 0; base < CHK; base += 1024) {
            int i0 = base + t;
            int d0 = dstp[i0],       d1 = dstp[i0 + 256],
                d2 = dstp[i0 + 512], d3 = dstp[i0 + 768];
            unsigned r0 = atomicAdd(&lcnt[d0 & (N - 1)], 1u);
            unsigned r1 = atomicAdd(&lcnt[d1 & (N - 1)], 1u);
            unsigned r2 = atomicAdd(&lcnt[d2 & (N - 1)], 1u);
            unsigned r3 = atomicAdd(&lcnt[d3 & (N - 1)], 1u);
            posp[i0]       = (unsigned short)r0;
            posp[i0 + 256] = (unsigned short)r1;
            posp[i0 + 512] = (unsigned short)r2;
            posp[i0 + 768] = (unsigned short)r3;
        }
        __syncthreads();
        for (int i = t; i < N; i += 256)
            bcnt[(((size_t)(g << 12) | i) << 3) + c] = (unsigned short)lcnt[i];
        return;
    }

    if (bid < 118) {  // pack blocks + sentinels
        int pb = bid - 64;
        if (pb == 0) {
            if (t < 4)  asrc[NT * H + t] = -1e30f;
            if (t < 64) reinterpret_cast<uint2*>(xpb)[(size_t)NT * 64 + t] = make_uint2(0u, 0u);
        }
        if (pb < 18) pack_body(W1, as1, ad1, pB1, pb * 256 + t);
        else         pack_body(W2, as2, ad2, pB2, (pb - 18) * 256 + t);
        return;
    }

    // ---- x0 + split for 8 nodes; graph g = actual XCD of this block ----
    int g   = bid & 7;
    int loc = (bid - 118) >> 3;               // bijective over (g, loc)
    int node = (g << 12) + (loc << 3) + (t >> 5);
    int q = t & 31;
    float4 v = reinterpret_cast<const float4*>(x)[node * 32 + q];
    ushort4 h, l;
    h.x = f2bf(v.x); l.x = f2bf(v.x - bf2f(h.x));
    h.y = f2bf(v.y); l.y = f2bf(v.y - bf2f(h.y));
    h.z = f2bf(v.z); l.z = f2bf(v.z - bf2f(h.z));
    h.w = f2bf(v.w); l.w = f2bf(v.w - bf2f(h.w));
    reinterpret_cast<ushort4*>(hi)[node * 32 + q] = h;
    reinterpret_cast<ushort4*>(lo)[node * 32 + q] = l;
    float s = v.x + v.y + v.z + v.w;
    #pragma unroll
    for (int o = 16; o; o >>= 1) s += __shfl_xor(s, o);
    if (q == 0) {
        int n = node & (N - 1);
        out[g * (3 * N) + n] = s * (1.0f / 128.0f);
    }
}

// ---- phase B: per-node chunk-prefix -> bases (in place), cnt, self-loop slot,
//      sentinel padding (disjoint from phase C's writes, safe to pre-pad) ----
__global__ __launch_bounds__(256) void k_basepad(
    unsigned short* __restrict__ bcnt, unsigned* __restrict__ cnt,
    int* __restrict__ slots)
{
    int bid = blockIdx.x;                     // 128 blocks, XCD-pinned
    int node = ((bid & 7) << 12) + ((bid >> 3) << 8) + threadIdx.x;
    ushort4* bp = reinterpret_cast<ushort4*>(bcnt + (size_t)node * 8);
    ushort4 lo = bp[0], hi = bp[1];
    unsigned b0 = 1;
    unsigned b1 = b0 + lo.x, b2 = b1 + lo.y, b3 = b2 + lo.z, b4 = b3 + lo.w;
    unsigned b5 = b4 + hi.x, b6 = b5 + hi.y, b7 = b6 + hi.z;
    unsigned deg = b7 + hi.w;                 // includes self-loop
    cnt[node] = deg;
    ushort4 wlo, whi;
    wlo.x = (unsigned short)b0; wlo.y = (unsigned short)b1;
    wlo.z = (unsigned short)b2; wlo.w = (unsigned short)b3;
    whi.x = (unsigned short)b4; whi.y = (unsigned short)b5;
    whi.z = (unsigned short)b6; whi.w = (unsigned short)b7;
    bp[0] = wlo; bp[1] = whi;
    int* sl = slots + (size_t)node * CAP;
    sl[0] = node * 4;                         // self-loop at slot 0
    int dpad = (((int)deg + 1) & ~1) + 14;    // covers 3-pair lookahead overshoot
    for (int i = (int)deg; i < dpad; ++i) sl[i] = NT * 4;
}

// ---- MFMA GEMM + (CB) phase-C atomic-free scatter blocks ----
template <int K, bool CB>
__global__ __launch_bounds__(256) void k_mfma(
    const unsigned short* __restrict__ Ahi, const unsigned short* __restrict__ Alo,
    const unsigned short* __restrict__ pB,
    unsigned short* __restrict__ xpb, float* __restrict__ asrc, float* __restrict__ adst,
    const int* __restrict__ ei, const unsigned short* __restrict__ pos,
    const unsigned short* __restrict__ bcnt, int* __restrict__ slots)
{
    constexpr int KT = K / 32;
    int t = threadIdx.x, lane = t & 63, w = t >> 6;

    if (CB && blockIdx.x >= NT / 64) {   // phase C: 512 blocks, 1024 edges each
        int cb = blockIdx.x - NT / 64;   // XCD g = cb&7 (512%8==0)
        int g = cb & 7, j = cb >> 3;     // j 0..63
        const int* srcp = ei + (size_t)g * EPB;
        const int* dstp = ei + E + (size_t)g * EPB;
        const unsigned short* posp = pos + (size_t)g * EPB;
        #pragma unroll
        for (int k2 = 0; k2 < 4; ++k2) {
            int eg = j * 1024 + k2 * 256 + t;
            int s = srcp[eg], d = dstp[eg];
            unsigned rank = posp[eg];
            unsigned base = bcnt[((size_t)d << 3) + (eg >> 13)];
            slots[(size_t)d * CAP + base + rank] = s * 4;
        }
        return;
    }

    int wm = w & 1, wn = w >> 1;
    int m0 = ((blockIdx.x & 7) << 12) + ((blockIdx.x >> 3) << 6) + wm * 32;
    int sBase = wn * 9;

    f32x4 acc[2][9];
    #pragma unroll
    for (int i = 0; i < 2; ++i)
        #pragma unroll
        for (int j = 0; j < 9; ++j)
            acc[i][j] = (f32x4){0.f, 0.f, 0.f, 0.f};

    int aRow = m0 + (lane & 15);
    int aCol = 8 * (lane >> 4);
    const unsigned short* a0h = Ahi + (size_t)aRow * K + aCol;
    const unsigned short* a0l = Alo + (size_t)aRow * K + aCol;
    const unsigned short* bp  = pB + ((size_t)sBase * 64 + lane) * 8;

    bf16x8 bc[9], bn[9];
    bf16x8 ah0c, al0c, ah1c, al1c, ah0n, al0n, ah1n, al1n;

    #pragma unroll
    for (int j = 0; j < 9; ++j) bc[j] = *reinterpret_cast<const bf16x8*>(bp + j * 512);
    ah0c = *reinterpret_cast<const bf16x8*>(a0h);
    al0c = *reinterpret_cast<const bf16x8*>(a0l);
    ah1c = *reinterpret_cast<const bf16x8*>(a0h + 16 * K);
    al1c = *reinterpret_cast<const bf16x8*>(a0l + 16 * K);

    #pragma unroll
    for (int kt = 0; kt < KT; ++kt) {
        if (kt + 1 < KT) {
            const unsigned short* bpn = bp + (size_t)(kt + 1) * NSLOT * 64 * 8;
            #pragma unroll
            for (int j = 0; j < 9; ++j) bn[j] = *reinterpret_cast<const bf16x8*>(bpn + j * 512);
            ah0n = *reinterpret_cast<const bf16x8*>(a0h + (kt + 1) * 32);
            al0n = *reinterpret_cast<const bf16x8*>(a0l + (kt + 1) * 32);
            ah1n = *reinterpret_cast<const bf16x8*>(a0h + 16 * K + (kt + 1) * 32);
            al1n = *reinterpret_cast<const bf16x8*>(a0l + 16 * K + (kt + 1) * 32);
        }
        __builtin_amdgcn_sched_barrier(0);   // keep prefetch loads ahead of MFMAs
        if (wn == 0) {
            #pragma unroll
            for (int j = 0; j < 9; ++j) {
                acc[0][j] = __builtin_amdgcn_mfma_f32_16x16x32_bf16(ah0c, bc[j], acc[0][j], 0, 0, 0);
                acc[1][j] = __builtin_amdgcn_mfma_f32_16x16x32_bf16(ah1c, bc[j], acc[1][j], 0, 0, 0);
                acc[0][j] = __builtin_amdgcn_mfma_f32_16x16x32_bf16(al0c, bc[j], acc[0][j], 0, 0, 0);
                acc[1][j] = __builtin_amdgcn_mfma_f32_16x16x32_bf16(al1c, bc[j], acc[1][j], 0, 0, 0);
            }
        } else {
            #pragma unroll
            for (int j = 0; j < 8; ++j) {
                acc[0][j] = __builtin_amdgcn_mfma_f32_16x16x32_bf16(ah0c, bc[j], acc[0][j], 0, 0, 0);
                acc[1][j] = __builtin_amdgcn_mfma_f32_16x16x32_bf16(ah1c, bc[j], acc[1][j], 0, 0, 0);
                acc[0][j] = __builtin_amdgcn_mfma_f32_16x16x32_bf16(al0c, bc[j], acc[0][j], 0, 0, 0);
                acc[1][j] = __builtin_amdgcn_mfma_f32_16x16x32_bf16(al1c, bc[j], acc[1][j], 0, 0, 0);
            }
            acc[0][7] = __builtin_amdgcn_mfma_f32_16x16x32_bf16(ah0c, bc[8], acc[0][7], 0, 0, 0);
            acc[1][7] = __builtin_amdgcn_mfma_f32_16x16x32_bf16(ah1c, bc[8], acc[1][7], 0, 0, 0);
        }
        if (kt + 1 < KT) {
            #pragma unroll
            for (int j = 0; j < 9; ++j) bc[j] = bn[j];
            ah0c = ah0n; al0c = al0n; ah1c = ah1n; al1c = al1n;
        }
    }

    // epilogue: C layout col = lane&15, row = (lane>>4)*4 + r  [m89-verified]
    #pragma unroll
    for (int mt = 0; mt < 2; ++mt) {
        int rowB = m0 + mt * 16 + (lane >> 4) * 4;
        if (wn == 0) {
            #pragma unroll
            for (int j = 0; j < 9; ++j) {
                int col = j * 16 + (lane & 15);
                #pragma unroll
                for (int r = 0; r < 4; ++r)
                    xpb[(size_t)(rowB + r) * D1 + col] = f2bf(acc[mt][j][r]);
            }
        } else {
            #pragma unroll
            for (int j = 0; j < 8; ++j) {
                int nt = 9 + j;
                int col = nt * 16 + (lane & 15);
                #pragma unroll
                for (int r = 0; r < 4; ++r) {
                    int row = rowB + r;
                    float v = acc[mt][j][r];
                    if (col < 256)      xpb[(size_t)row * D1 + col] = f2bf(v);
                    else if (col < 260) asrc[row * H + (col - 256)] = v;
                    else if (col < 264) adst[row * H + (col - 260)] = v;
                }
            }
        }
    }
}

// ---- node aggregation: one wave per node; half-wave per edge (2 edges/step);
//      packed-f32 FMA + 3-slot circular prefetch (6 edges in flight) ----
__global__ __launch_bounds__(256) void k_node(
    const unsigned* __restrict__ cnt, const int* __restrict__ slots,
    const float* __restrict__ asrc, const float* __restrict__ adst,
    const unsigned short* __restrict__ xp,   // bf16 [NT+1][256]
    const float* __restrict__ bias, const float* __restrict__ pw,
    const float* __restrict__ pb,
    unsigned short* __restrict__ hhi, unsigned short* __restrict__ hlo,
    float* __restrict__ out, int sec)
{
    int bid = blockIdx.x;
    int w = threadIdx.x >> 6, lane = threadIdx.x & 63;
    int half = lane >> 5;                     // which edge of the pair
    int hl   = lane & 31;                     // lane within half: ch 8*hl..8*hl+7
    int head = hl >> 3;                       // 8 lanes per head
    // graph g = bid&7 pinned to XCD g; 4 nodes per block (one per wave)
    int node = ((bid & 7) << 12) | (((bid >> 3) << 2) + w);

    int deg = (int)cnt[node];                 // >= 1 (self loop)
    int dp  = (deg + 1) & ~1;                 // pair-rounded; overshoot hits sentinels
    const int* sl = slots + (size_t)node * CAP;
    float adh = adst[node * H + head];
    const uint4* xp4 = (const uint4*)xp;      // 8 bf16 per lane

    float den = 0.f;
    pk2 acc01 = {0.f, 0.f}, acc23 = {0.f, 0.f}, acc45 = {0.f, 0.f}, acc67 = {0.f, 0.f};

    #define PROC(aa, vv)                                                     \
    {                                                                        \
        float l  = aa + adh;                                                 \
        float ev = __expf(fmaxf(l, 0.2f * l));                               \
        den += ev;                                                           \
        pk2 e2 = {ev, ev};                                                   \
        pk2 t01 = {__uint_as_float(vv.x << 16), __uint_as_float(vv.x & 0xFFFF0000u)}; \
        pk2 t23 = {__uint_as_float(vv.y << 16), __uint_as_float(vv.y & 0xFFFF0000u)}; \
        pk2 t45 = {__uint_as_float(vv.z << 16), __uint_as_float(vv.z & 0xFFFF0000u)}; \
        pk2 t67 = {__uint_as_float(vv.w << 16), __uint_as_float(vv.w & 0xFFFF0000u)}; \
        acc01 = __builtin_elementwise_fma(e2, t01, acc01);                   \
        acc23 = __builtin_elementwise_fma(e2, t23, acc23);                   \
        acc45 = __builtin_elementwise_fma(e2, t45, acc45);                   \
        acc67 = __builtin_elementwise_fma(e2, t67, acc67);                   \
    }

    // 3-slot circular prefetch: pairs 0,2,4 preloaded; prefetch i+6 before use
    int   s_;
    float aX, aY, aZ, a_;
    uint4 vX, vY, vZ, v_;
    s_ = sl[0 + half]; aX = asrc[s_ + head]; vX = xp4[(s_ << 3) + hl];
    s_ = sl[2 + half]; aY = asrc[s_ + head]; vY = xp4[(s_ << 3) + hl];
    s_ = sl[4 + half]; aZ = asrc[s_ + head]; vZ = xp4[(s_ << 3) + hl];

    for (int i = 0; i < dp; i += 6) {
        s_ = sl[i + 6 + half];  a_ = asrc[s_ + head]; v_ = xp4[(s_ << 3) + hl];
        PROC(aX, vX); aX = a_; vX = v_;
        s_ = sl[i + 8 + half];  a_ = asrc[s_ + head]; v_ = xp4[(s_ << 3) + hl];
        PROC(aY, vY); aY = a_; vY = v_;
        s_ = sl[i + 10 + half]; a_ = asrc[s_ + head]; v_ = xp4[(s_ << 3) + hl];
        PROC(aZ, vZ); aZ = a_; vZ = v_;
    }
    #undef PROC

    // combine the two halves (lane l <-> l^32 hold same channels, different edges)
    den      += __shfl_xor(den, 32);
    acc01[0] += __shfl_xor(acc01[0], 32);
    acc01[1] += __shfl_xor(acc01[1], 32);
    acc23[0] += __shfl_xor(acc23[0], 32);
    acc23[1] += __shfl_xor(acc23[1], 32);
    acc45[0] += __shfl_xor(acc45[0], 32);
    acc45[1] += __shfl_xor(acc45[1], 32);
    acc67[0] += __shfl_xor(acc67[0], 32);
    acc67[1] += __shfl_xor(acc67[1], 32);

    float invd = 1.f / (den + 1e-16f);
    float4 b0 = reinterpret_cast<const float4*>(bias)[hl * 2];
    float4 b1 = reinterpret_cast<const float4*>(bias)[hl * 2 + 1];
    float4 p0 = reinterpret_cast<const float4*>(pw)[hl * 2];
    float4 p1 = reinterpret_cast<const float4*>(pw)[hl * 2 + 1];

    float h0 = fmaf(acc01[0], invd, b0.x), h1 = fmaf(acc01[1], invd, b0.y),
          h2 = fmaf(acc23[0], invd, b0.z), h3 = fmaf(acc23[1], invd, b0.w),
          h4 = fmaf(acc45[0], invd, b1.x), h5 = fmaf(acc45[1], invd, b1.y),
          h6 = fmaf(acc67[0], invd, b1.z), h7 = fmaf(acc67[1], invd, b1.w);
    h0 = h0 > 0.f ? h0 : __expf(h0) - 1.f;
    h1 = h1 > 0.f ? h1 : __expf(h1) - 1.f;
    h2 = h2 > 0.f ? h2 : __expf(h2) - 1.f;
    h3 = h3 > 0.f ? h3 : __expf(h3) - 1.f;
    h4 = h4 > 0.f ? h4 : __expf(h4) - 1.f;
    h5 = h5 > 0.f ? h5 : __expf(h5) - 1.f;
    h6 = h6 > 0.f ? h6 : __expf(h6) - 1.f;
    h7 = h7 > 0.f ? h7 : __expf(h7) - 1.f;

    if (hhi && half == 0) {
        unsigned short q0 = f2bf(h0), q1 = f2bf(h1), q2 = f2bf(h2), q3 = f2bf(h3),
                       q4 = f2bf(h4), q5 = f2bf(h5), q6 = f2bf(h6), q7 = f2bf(h7);
        uint4 hw, lw;
        hw.x = (unsigned)q0 | ((unsigned)q1 << 16);
        hw.y = (unsigned)q2 | ((unsigned)q3 << 16);
        hw.z = (unsigned)q4 | ((unsigned)q5 << 16);
        hw.w = (unsigned)q6 | ((unsigned)q7 << 16);
        lw.x = (unsigned)f2bf(h0 - bf2f(q0)) | ((unsigned)f2bf(h1 - bf2f(q1)) << 16);
        lw.y = (unsigned)f2bf(h2 - bf2f(q2)) | ((unsigned)f2bf(h3 - bf2f(q3)) << 16);
        lw.z = (unsigned)f2bf(h4 - bf2f(q4)) | ((unsigned)f2bf(h5 - bf2f(q5)) << 16);
        lw.w = (unsigned)f2bf(h6 - bf2f(q6)) | ((unsigned)f2bf(h7 - bf2f(q7)) << 16);
        reinterpret_cast<uint4*>(hhi)[node * 32 + hl] = hw;
        reinterpret_cast<uint4*>(hlo)[node * 32 + hl] = lw;
    }

    float p = h0 * p0.x + h1 * p0.y + h2 * p0.z + h3 * p0.w
            + h4 * p1.x + h5 * p1.y + h6 * p1.z + h7 * p1.w;
    #pragma unroll
    for (int o = 16; o; o >>= 1) p += __shfl_xor(p, o);
    if (lane == 0) {
        int b = node >> 12;
        int n = node & (N - 1);
        out[b * (3 * N) + sec * N + n] = p + pb[0];
    }
}

extern "C" void kernel_launch(void* const* d_in, const int* in_sizes, int n_in,
                              void* d_out, int out_size, void* d_ws, size_t ws_size,
                              hipStream_t stream) {
    const float* x   = (const float*)d_in[0];
    const int*   ei  = (const int*)d_in[1];
    const float* W1  = (const float*)d_in[2];
    const float* as1 = (const float*)d_in[3];
    const float* ad1 = (const float*)d_in[4];
    const float* b1  = (const float*)d_in[5];
    const float* W2  = (const float*)d_in[6];
    const float* as2 = (const float*)d_in[7];
    const float* ad2 = (const float*)d_in[8];
    const float* b2  = (const float*)d_in[9];
    const float* pw1 = (const float*)d_in[10];
    const float* pb1 = (const float*)d_in[11];
    const float* pw2 = (const float*)d_in[12];
    const float* pb2 = (const float*)d_in[13];
    float* out = (float*)d_out;

    // workspace layout (16B aligned blocks); xpb/asrc have +1 sentinel row
    unsigned short* xpb  = (unsigned short*)d_ws;             // (NT+1)*D1 bf16
    unsigned short* xhi  = xpb  + (size_t)(NT + 1) * D1;      // NT*FIN
    unsigned short* xlo  = xhi  + (size_t)NT * FIN;           // NT*FIN
    unsigned short* h1hi = xlo  + (size_t)NT * FIN;           // NT*D1
    unsigned short* h1lo = h1hi + (size_t)NT * D1;            // NT*D1
    float*    asrc   = (float*)(h1lo + (size_t)NT * D1);      // (NT+1)*H
    float*    adst   = asrc + (size_t)(NT + 1) * H;           // NT*H
    unsigned short* pB1 = (unsigned short*)(adst + (size_t)NT * H); // 4*18*64*8
    unsigned short* pB2 = pB1 + (size_t)4 * NSLOT * 64 * 8;         // 8*18*64*8
    unsigned* cnt    = (unsigned*)(pB2 + (size_t)8 * NSLOT * 64 * 8); // NT
    int*      slots  = (int*)(cnt + NT);                      // NT*CAP
    unsigned short* pos  = (unsigned short*)(slots + (size_t)NT * CAP); // E
    unsigned short* bcnt = pos + (size_t)E;                   // NT*8

    // 6 dispatches, zero global atomics
    k_combo<<<118 + NT / 8, 256, 0, stream>>>(x, ei, xhi, xlo, out, pos, bcnt,
                                              W1, as1, ad1, W2, as2, ad2, pB1, pB2,
                                              asrc, xpb);
    k_basepad<<<128, 256, 0, stream>>>(bcnt, cnt, slots);

    // ---------------- layer 1 (K = 128) + phase-C scatter ----------------
    k_mfma<128, true><<<NT / 64 + 512, 256, 0, stream>>>(
        xhi, xlo, pB1, xpb, asrc, adst, ei, pos, bcnt, slots);
    k_node<<<NT / 4, 256, 0, stream>>>(cnt, slots, asrc, adst, xpb,
                                       b1, pw1, pb1, h1hi, h1lo, out, 1);

    // ---------------- layer 2 (K = 256) ----------------
    k_mfma<256, false><<<NT / 64, 256, 0, stream>>>(
        h1hi, h1lo, pB2, xpb, asrc, adst, nullptr, nullptr, nullptr, nullptr);
    k_node<<<NT / 4, 256, 0, stream>>>(cnt, slots, asrc, adst, xpb,
                                       b2, pw2, pb2, nullptr, nullptr, out, 2);
}

// Round 16
// 111.860 us; speedup vs baseline: 1.3170x; 1.0361x over previous
//
#include <hip/hip_runtime.h>

typedef __attribute__((ext_vector_type(8))) short bf16x8;
typedef __attribute__((ext_vector_type(4))) float f32x4;
typedef __attribute__((ext_vector_type(2))) float pk2;

// Problem constants (from reference)
constexpr int B    = 8;
constexpr int N    = 4096;
constexpr int FIN  = 128;
constexpr int NT   = B * N;        // 32768
constexpr int H    = 4;
constexpr int C    = 64;
constexpr int D1   = H * C;        // 256
constexpr int E    = 524288;
constexpr int EPB  = E / B;        // 65536 main edges per graph (graph-sorted)
constexpr int CHK  = 8192;         // edges per phase-A chunk (8 chunks/graph)
constexpr int NSLOT = 18;          // per-kt B slots: 0..16 = bh(nt0..16), 17 = blAtt(nt16)
constexpr int CAP  = 64;           // adjacency bucket capacity (max deg ~40)

// bf16 round-to-nearest-even helpers
__device__ __forceinline__ unsigned short f2bf(float f) {
    unsigned u = __float_as_uint(f);
    return (unsigned short)((u + 0x7FFFu + ((u >> 16) & 1u)) >> 16);
}
__device__ __forceinline__ float bf2f(unsigned short b) {
    return __uint_as_float(((unsigned)b) << 16);
}

// ---- pack one layer's Bext = [W | Ws | Wd | 0] into per-kt slot layout ----
__device__ __forceinline__ void pack_body(
    const float* __restrict__ W, const float* __restrict__ as_,
    const float* __restrict__ ad_, unsigned short* __restrict__ pB, int g)
{
    int kt  = g / (NSLOT * 64);
    int rem = g % (NSLOT * 64);
    int slot = rem >> 6, l = rem & 63;
    int k0 = kt * 32 + 8 * (l >> 4);
    bool wantLo = (slot == 17);
    int nt = wantLo ? 16 : slot;
    int n  = nt * 16 + (l & 15);
    bf16x8 o;
    #pragma unroll
    for (int j = 0; j < 8; ++j) {
        int k = k0 + j;
        float v;
        if (n < 256) {
            v = W[k * D1 + n];
        } else if (n < 264) {
            int idx = n - 256, hh = idx & 3;
            const float* av = (idx < 4) ? as_ : ad_;
            float s = 0.f;
            #pragma unroll 8
            for (int c = 0; c < C; ++c) s += W[k * D1 + hh * C + c] * av[hh * C + c];
            v = s;
        } else {
            v = 0.f;
        }
        unsigned short hb = f2bf(v);
        o[j] = wantLo ? (short)f2bf(v - bf2f(hb)) : (short)hb;
    }
    *reinterpret_cast<bf16x8*>(pB + (size_t)g * 8) = o;
}

// ---- fused: phase-A rank-capture histogram (bid<64) | pack+sentinels (64..117)
//      | x0 + split (bid>=118, XCD-pinned via g = bid&7) ----
__global__ __launch_bounds__(256) void k_combo(
    const float* __restrict__ x, const int* __restrict__ ei,
    unsigned short* __restrict__ hi, unsigned short* __restrict__ lo,
    float* __restrict__ out,
    unsigned short* __restrict__ pos, unsigned short* __restrict__ bcnt,
    const float* __restrict__ W1, const float* __restrict__ as1, const float* __restrict__ ad1,
    const float* __restrict__ W2, const float* __restrict__ as2, const float* __restrict__ ad2,
    unsigned short* __restrict__ pB1, unsigned short* __restrict__ pB2,
    float* __restrict__ asrc, unsigned short* __restrict__ xpb)
{
    __shared__ unsigned lcnt[N];              // 16 KB (phase-A blocks only)
    int bid = blockIdx.x, t = threadIdx.x;

    if (bid < 64) {
        // ---- phase A: graph g, chunk c; LDS histogram + per-edge local rank ----
        int g = bid & 7, c = bid >> 3;        // block -> XCD g
        for (int i = t; i < N; i += 256) lcnt[i] = 0u;
        __syncthreads();
        const int* dstp = ei + E + (size_t)g * EPB + (size_t)c * CHK;
        unsigned short* posp = pos + (size_t)g * EPB + (size_t)c * CHK;
        for (int base = 0; base < CHK; base += 1024) {
            int i0 = base + t;
            int d0 = dstp[i0],       d1 = dstp[i0 + 256],
                d2 = dstp[i0 + 512], d3 = dstp[i0 + 768];
            unsigned r0 = atomicAdd(&lcnt[d0 & (N - 1)], 1u);
            unsigned r1 = atomicAdd(&lcnt[d1 & (N - 1)], 1u);
            unsigned r2 = atomicAdd(&lcnt[d2 & (N - 1)], 1u);
            unsigned r3 = atomicAdd(&lcnt[d3 & (N - 1)], 1u);
            posp[i0]       = (unsigned short)r0;
            posp[i0 + 256] = (unsigned short)r1;
            posp[i0 + 512] = (unsigned short)r2;
            posp[i0 + 768] = (unsigned short)r3;
        }
        __syncthreads();
        for (int i = t; i < N; i += 256)
            bcnt[(((size_t)(g << 12) | i) << 3) + c] = (unsigned short)lcnt[i];
        return;
    }

    if (bid < 118) {  // pack blocks + sentinel rows
        int pb = bid - 64;
        if (pb == 0) {
            if (t < 4)  asrc[NT * H + t] = -1e30f;
            if (t < 64) reinterpret_cast<uint2*>(xpb)[(size_t)NT * 64 + t] = make_uint2(0u, 0u);
        }
        if (pb < 18) pack_body(W1, as1, ad1, pB1, pb * 256 + t);
        else         pack_body(W2, as2, ad2, pB2, (pb - 18) * 256 + t);
        return;
    }

    // ---- x0 + split for 8 nodes; graph g = actual XCD of this block ----
    int g   = bid & 7;
    int loc = (bid - 118) >> 3;               // bijective over (g, loc)
    int node = (g << 12) + (loc << 3) + (t >> 5);
    int q = t & 31;
    float4 v = reinterpret_cast<const float4*>(x)[node * 32 + q];
    ushort4 h, l;
    h.x = f2bf(v.x); l.x = f2bf(v.x - bf2f(h.x));
    h.y = f2bf(v.y); l.y = f2bf(v.y - bf2f(h.y));
    h.z = f2bf(v.z); l.z = f2bf(v.z - bf2f(h.z));
    h.w = f2bf(v.w); l.w = f2bf(v.w - bf2f(h.w));
    reinterpret_cast<ushort4*>(hi)[node * 32 + q] = h;
    reinterpret_cast<ushort4*>(lo)[node * 32 + q] = l;
    float s = v.x + v.y + v.z + v.w;
    #pragma unroll
    for (int o = 16; o; o >>= 1) s += __shfl_xor(s, o);
    if (q == 0) {
        int n = node & (N - 1);
        out[g * (3 * N) + n] = s * (1.0f / 128.0f);
    }
}

// ---- phase B: chunk-prefix -> bases (in place), cnt, FULL sentinel row fill
//      (coalesced int4, whole 64-slot row), then self-loop slot 0.
//      Phase C (next kernel) overwrites [1, deg). ----
__global__ __launch_bounds__(256) void k_basepad(
    unsigned short* __restrict__ bcnt, unsigned* __restrict__ cnt,
    int* __restrict__ slots)
{
    int bid = blockIdx.x;                     // 128 blocks, XCD-pinned
    int t = threadIdx.x;
    int nbase = ((bid & 7) << 12) + ((bid >> 3) << 8);
    int node = nbase + t;

    // cooperative sentinel fill of this block's 256 rows (4096 int4, 16 coalesced stores)
    int4* base4 = reinterpret_cast<int4*>(slots + (size_t)nbase * CAP);
    int4 sent = make_int4(NT * 4, NT * 4, NT * 4, NT * 4);
    #pragma unroll
    for (int i = 0; i < 16; ++i) base4[i * 256 + t] = sent;

    ushort4* bp = reinterpret_cast<ushort4*>(bcnt + (size_t)node * 8);
    ushort4 lo = bp[0], hi = bp[1];
    unsigned b0 = 1;
    unsigned b1 = b0 + lo.x, b2 = b1 + lo.y, b3 = b2 + lo.z, b4 = b3 + lo.w;
    unsigned b5 = b4 + hi.x, b6 = b5 + hi.y, b7 = b6 + hi.z;
    unsigned deg = b7 + hi.w;                 // includes self-loop
    cnt[node] = deg;
    ushort4 wlo, whi;
    wlo.x = (unsigned short)b0; wlo.y = (unsigned short)b1;
    wlo.z = (unsigned short)b2; wlo.w = (unsigned short)b3;
    whi.x = (unsigned short)b4; whi.y = (unsigned short)b5;
    whi.z = (unsigned short)b6; whi.w = (unsigned short)b7;
    bp[0] = wlo; bp[1] = whi;

    __syncthreads();                          // sentinels before self-loop write
    slots[(size_t)node * CAP] = node * 4;     // self-loop at slot 0
}

// ---- MFMA GEMM + (CB) phase-C atomic-free scatter blocks ----
template <int K, bool CB>
__global__ __launch_bounds__(256) void k_mfma(
    const unsigned short* __restrict__ Ahi, const unsigned short* __restrict__ Alo,
    const unsigned short* __restrict__ pB,
    unsigned short* __restrict__ xpb, float* __restrict__ asrc, float* __restrict__ adst,
    const int* __restrict__ ei, const unsigned short* __restrict__ pos,
    const unsigned short* __restrict__ bcnt, int* __restrict__ slots)
{
    constexpr int KT = K / 32;
    int t = threadIdx.x, lane = t & 63, w = t >> 6;

    if (CB && blockIdx.x >= NT / 64) {   // phase C: 512 blocks, 1024 edges each
        int cb = blockIdx.x - NT / 64;   // XCD g = cb&7 (512%8==0)
        int g = cb & 7, j = cb >> 3;     // j 0..63
        const int* srcp = ei + (size_t)g * EPB;
        const int* dstp = ei + E + (size_t)g * EPB;
        const unsigned short* posp = pos + (size_t)g * EPB;
        #pragma unroll
        for (int k2 = 0; k2 < 4; ++k2) {
            int eg = j * 1024 + k2 * 256 + t;
            int s = srcp[eg], d = dstp[eg];
            unsigned rank = posp[eg];
            unsigned base = bcnt[((size_t)d << 3) + (eg >> 13)];
            slots[(size_t)d * CAP + base + rank] = s * 4;
        }
        return;
    }

    int wm = w & 1, wn = w >> 1;
    int m0 = ((blockIdx.x & 7) << 12) + ((blockIdx.x >> 3) << 6) + wm * 32;
    int sBase = wn * 9;

    f32x4 acc[2][9];
    #pragma unroll
    for (int i = 0; i < 2; ++i)
        #pragma unroll
        for (int j = 0; j < 9; ++j)
            acc[i][j] = (f32x4){0.f, 0.f, 0.f, 0.f};

    int aRow = m0 + (lane & 15);
    int aCol = 8 * (lane >> 4);
    const unsigned short* a0h = Ahi + (size_t)aRow * K + aCol;
    const unsigned short* a0l = Alo + (size_t)aRow * K + aCol;
    const unsigned short* bp  = pB + ((size_t)sBase * 64 + lane) * 8;

    bf16x8 bc[9], bn[9];
    bf16x8 ah0c, al0c, ah1c, al1c, ah0n, al0n, ah1n, al1n;

    #pragma unroll
    for (int j = 0; j < 9; ++j) bc[j] = *reinterpret_cast<const bf16x8*>(bp + j * 512);
    ah0c = *reinterpret_cast<const bf16x8*>(a0h);
    al0c = *reinterpret_cast<const bf16x8*>(a0l);
    ah1c = *reinterpret_cast<const bf16x8*>(a0h + 16 * K);
    al1c = *reinterpret_cast<const bf16x8*>(a0l + 16 * K);

    #pragma unroll
    for (int kt = 0; kt < KT; ++kt) {
        if (kt + 1 < KT) {
            const unsigned short* bpn = bp + (size_t)(kt + 1) * NSLOT * 64 * 8;
            #pragma unroll
            for (int j = 0; j < 9; ++j) bn[j] = *reinterpret_cast<const bf16x8*>(bpn + j * 512);
            ah0n = *reinterpret_cast<const bf16x8*>(a0h + (kt + 1) * 32);
            al0n = *reinterpret_cast<const bf16x8*>(a0l + (kt + 1) * 32);
            ah1n = *reinterpret_cast<const bf16x8*>(a0h + 16 * K + (kt + 1) * 32);
            al1n = *reinterpret_cast<const bf16x8*>(a0l + 16 * K + (kt + 1) * 32);
        }
        __builtin_amdgcn_sched_barrier(0);   // keep prefetch loads ahead of MFMAs
        if (wn == 0) {
            #pragma unroll
            for (int j = 0; j < 9; ++j) {
                acc[0][j] = __builtin_amdgcn_mfma_f32_16x16x32_bf16(ah0c, bc[j], acc[0][j], 0, 0, 0);
                acc[1][j] = __builtin_amdgcn_mfma_f32_16x16x32_bf16(ah1c, bc[j], acc[1][j], 0, 0, 0);
                acc[0][j] = __builtin_amdgcn_mfma_f32_16x16x32_bf16(al0c, bc[j], acc[0][j], 0, 0, 0);
                acc[1][j] = __builtin_amdgcn_mfma_f32_16x16x32_bf16(al1c, bc[j], acc[1][j], 0, 0, 0);
            }
        } else {
            #pragma unroll
            for (int j = 0; j < 8; ++j) {
                acc[0][j] = __builtin_amdgcn_mfma_f32_16x16x32_bf16(ah0c, bc[j], acc[0][j], 0, 0, 0);
                acc[1][j] = __builtin_amdgcn_mfma_f32_16x16x32_bf16(ah1c, bc[j], acc[1][j], 0, 0, 0);
                acc[0][j] = __builtin_amdgcn_mfma_f32_16x16x32_bf16(al0c, bc[j], acc[0][j], 0, 0, 0);
                acc[1][j] = __builtin_amdgcn_mfma_f32_16x16x32_bf16(al1c, bc[j], acc[1][j], 0, 0, 0);
            }
            acc[0][7] = __builtin_amdgcn_mfma_f32_16x16x32_bf16(ah0c, bc[8], acc[0][7], 0, 0, 0);
            acc[1][7] = __builtin_amdgcn_mfma_f32_16x16x32_bf16(ah1c, bc[8], acc[1][7], 0, 0, 0);
        }
        if (kt + 1 < KT) {
            #pragma unroll
            for (int j = 0; j < 9; ++j) bc[j] = bn[j];
            ah0c = ah0n; al0c = al0n; ah1c = ah1n; al1c = al1n;
        }
    }

    // epilogue: C layout col = lane&15, row = (lane>>4)*4 + r  [m89-verified]
    #pragma unroll
    for (int mt = 0; mt < 2; ++mt) {
        int rowB = m0 + mt * 16 + (lane >> 4) * 4;
        if (wn == 0) {
            #pragma unroll
            for (int j = 0; j < 9; ++j) {
                int col = j * 16 + (lane & 15);
                #pragma unroll
                for (int r = 0; r < 4; ++r)
                    xpb[(size_t)(rowB + r) * D1 + col] = f2bf(acc[mt][j][r]);
            }
        } else {
            #pragma unroll
            for (int j = 0; j < 8; ++j) {
                int nt = 9 + j;
                int col = nt * 16 + (lane & 15);
                #pragma unroll
                for (int r = 0; r < 4; ++r) {
                    int row = rowB + r;
                    float v = acc[mt][j][r];
                    if (col < 256)      xpb[(size_t)row * D1 + col] = f2bf(v);
                    else if (col < 260) asrc[row * H + (col - 256)] = v;
                    else if (col < 264) adst[row * H + (col - 260)] = v;
                }
            }
        }
    }
}

// ---- node aggregation: one wave per node; half-wave per edge;
//      LANE-RESIDENT slot indices (one coalesced load + shfl broadcast),
//      4-pair-deep prefetch (8 edges in flight), packed-f32 FMA ----
__global__ __launch_bounds__(256) void k_node(
    const unsigned* __restrict__ cnt, const int* __restrict__ slots,
    const float* __restrict__ asrc, const float* __restrict__ adst,
    const unsigned short* __restrict__ xp,   // bf16 [NT+1][256]
    const float* __restrict__ bias, const float* __restrict__ pw,
    const float* __restrict__ pb,
    unsigned short* __restrict__ hhi, unsigned short* __restrict__ hlo,
    float* __restrict__ out, int sec)
{
    int bid = blockIdx.x;
    int w = threadIdx.x >> 6, lane = threadIdx.x & 63;
    int half = lane >> 5;                     // which edge of the pair
    int hl   = lane & 31;                     // lane within half: ch 8*hl..8*hl+7
    int head = hl >> 3;                       // 8 lanes per head
    // graph g = bid&7 pinned to XCD g; 4 nodes per block (one per wave)
    int node = ((bid & 7) << 12) | (((bid >> 3) << 2) + w);

    int deg = (int)cnt[node];                 // >= 1 (self loop)
    int dp  = (deg + 1) & ~1;                 // pair-rounded; overshoot hits sentinels
    const int* sl = slots + (size_t)node * CAP;
    int myslot = sl[lane];                    // all 64 slots -> registers (1 load)
    float adh = adst[node * H + head];
    const float* asrcH = asrc + head;
    const uint4* xpL = (const uint4*)xp + hl;

    float den = 0.f;
    pk2 acc01 = {0.f, 0.f}, acc23 = {0.f, 0.f}, acc45 = {0.f, 0.f}, acc67 = {0.f, 0.f};

    #define PROC(aa, vv)                                                     \
    {                                                                        \
        float l  = aa + adh;                                                 \
        float ev = __expf(fmaxf(l, 0.2f * l));                               \
        den += ev;                                                           \
        pk2 e2 = {ev, ev};                                                   \
        pk2 t01 = {__uint_as_float(vv.x << 16), __uint_as_float(vv.x & 0xFFFF0000u)}; \
        pk2 t23 = {__uint_as_float(vv.y << 16), __uint_as_float(vv.y & 0xFFFF0000u)}; \
        pk2 t45 = {__uint_as_float(vv.z << 16), __uint_as_float(vv.z & 0xFFFF0000u)}; \
        pk2 t67 = {__uint_as_float(vv.w << 16), __uint_as_float(vv.w & 0xFFFF0000u)}; \
        acc01 = __builtin_elementwise_fma(e2, t01, acc01);                   \
        acc23 = __builtin_elementwise_fma(e2, t23, acc23);                   \
        acc45 = __builtin_elementwise_fma(e2, t45, acc67 * 0.f + acc23);     \
        acc45 = __builtin_elementwise_fma(e2, t45, acc45);                   \
        acc67 = __builtin_elementwise_fma(e2, t67, acc67);                   \
    }
    #undef PROC
    #define PROC(aa, vv)                                                     \
    {                                                                        \
        float l  = aa + adh;                                                 \
        float ev = __expf(fmaxf(l, 0.2f * l));                               \
        den += ev;                                                           \
        pk2 e2 = {ev, ev};                                                   \
        pk2 t01 = {__uint_as_float(vv.x << 16), __uint_as_float(vv.x & 0xFFFF0000u)}; \
        pk2 t23 = {__uint_as_float(vv.y << 16), __uint_as_float(vv.y & 0xFFFF0000u)}; \
        pk2 t45 = {__uint_as_float(vv.z << 16), __uint_as_float(vv.z & 0xFFFF0000u)}; \
        pk2 t67 = {__uint_as_float(vv.w << 16), __uint_as_float(vv.w & 0xFFFF0000u)}; \
        acc01 = __builtin_elementwise_fma(e2, t01, acc01);                   \
        acc23 = __builtin_elementwise_fma(e2, t23, acc23);                   \
        acc45 = __builtin_elementwise_fma(e2, t45, acc45);                   \
        acc67 = __builtin_elementwise_fma(e2, t67, acc67);                   \
    }

    // 4-pair prefetch via shfl-broadcast slot indices (8 edges in flight)
    float aA, aB, aC, aD;
    uint4 vA, vB, vC, vD;
    {
        int s0 = __shfl(myslot, 0 + half);
        int s1 = __shfl(myslot, 2 + half);
        int s2 = __shfl(myslot, 4 + half);
        int s3 = __shfl(myslot, 6 + half);
        aA = asrcH[s0]; vA = xpL[(size_t)s0 << 3];
        aB = asrcH[s1]; vB = xpL[(size_t)s1 << 3];
        aC = asrcH[s2]; vC = xpL[(size_t)s2 << 3];
        aD = asrcH[s3]; vD = xpL[(size_t)s3 << 3];
    }

    for (int i = 0; i < dp; i += 8) {
        int s0 = __shfl(myslot, i + 8 + half);
        int s1 = __shfl(myslot, i + 10 + half);
        int s2 = __shfl(myslot, i + 12 + half);
        int s3 = __shfl(myslot, i + 14 + half);
        float b0 = asrcH[s0], b1 = asrcH[s1], b2 = asrcH[s2], b3 = asrcH[s3];
        uint4 w0 = xpL[(size_t)s0 << 3], w1 = xpL[(size_t)s1 << 3],
              w2 = xpL[(size_t)s2 << 3], w3 = xpL[(size_t)s3 << 3];

        PROC(aA, vA);
        PROC(aB, vB);
        PROC(aC, vC);
        PROC(aD, vD);

        aA = b0; vA = w0; aB = b1; vB = w1;
        aC = b2; vC = w2; aD = b3; vD = w3;
    }
    #undef PROC

    // combine the two halves (lane l <-> l^32 hold same channels, different edges)
    den      += __shfl_xor(den, 32);
    acc01[0] += __shfl_xor(acc01[0], 32);
    acc01[1] += __shfl_xor(acc01[1], 32);
    acc23[0] += __shfl_xor(acc23[0], 32);
    acc23[1] += __shfl_xor(acc23[1], 32);
    acc45[0] += __shfl_xor(acc45[0], 32);
    acc45[1] += __shfl_xor(acc45[1], 32);
    acc67[0] += __shfl_xor(acc67[0], 32);
    acc67[1] += __shfl_xor(acc67[1], 32);

    float invd = 1.f / (den + 1e-16f);
    float4 b0 = reinterpret_cast<const float4*>(bias)[hl * 2];
    float4 b1 = reinterpret_cast<const float4*>(bias)[hl * 2 + 1];
    float4 p0 = reinterpret_cast<const float4*>(pw)[hl * 2];
    float4 p1 = reinterpret_cast<const float4*>(pw)[hl * 2 + 1];

    float h0 = fmaf(acc01[0], invd, b0.x), h1 = fmaf(acc01[1], invd, b0.y),
          h2 = fmaf(acc23[0], invd, b0.z), h3 = fmaf(acc23[1], invd, b0.w),
          h4 = fmaf(acc45[0], invd, b1.x), h5 = fmaf(acc45[1], invd, b1.y),
          h6 = fmaf(acc67[0], invd, b1.z), h7 = fmaf(acc67[1], invd, b1.w);
    h0 = h0 > 0.f ? h0 : __expf(h0) - 1.f;
    h1 = h1 > 0.f ? h1 : __expf(h1) - 1.f;
    h2 = h2 > 0.f ? h2 : __expf(h2) - 1.f;
    h3 = h3 > 0.f ? h3 : __expf(h3) - 1.f;
    h4 = h4 > 0.f ? h4 : __expf(h4) - 1.f;
    h5 = h5 > 0.f ? h5 : __expf(h5) - 1.f;
    h6 = h6 > 0.f ? h6 : __expf(h6) - 1.f;
    h7 = h7 > 0.f ? h7 : __expf(h7) - 1.f;

    if (hhi && half == 0) {
        unsigned short q0 = f2bf(h0), q1 = f2bf(h1), q2 = f2bf(h2), q3 = f2bf(h3),
                       q4 = f2bf(h4), q5 = f2bf(h5), q6 = f2bf(h6), q7 = f2bf(h7);
        uint4 hw, lw;
        hw.x = (unsigned)q0 | ((unsigned)q1 << 16);
        hw.y = (unsigned)q2 | ((unsigned)q3 << 16);
        hw.z = (unsigned)q4 | ((unsigned)q5 << 16);
        hw.w = (unsigned)q6 | ((unsigned)q7 << 16);
        lw.x = (unsigned)f2bf(h0 - bf2f(q0)) | ((unsigned)f2bf(h1 - bf2f(q1)) << 16);
        lw.y = (unsigned)f2bf(h2 - bf2f(q2)) | ((unsigned)f2bf(h3 - bf2f(q3)) << 16);
        lw.z = (unsigned)f2bf(h4 - bf2f(q4)) | ((unsigned)f2bf(h5 - bf2f(q5)) << 16);
        lw.w = (unsigned)f2bf(h6 - bf2f(q6)) | ((unsigned)f2bf(h7 - bf2f(q7)) << 16);
        reinterpret_cast<uint4*>(hhi)[node * 32 + hl] = hw;
        reinterpret_cast<uint4*>(hlo)[node * 32 + hl] = lw;
    }

    float p = h0 * p0.x + h1 * p0.y + h2 * p0.z + h3 * p0.w
            + h4 * p1.x + h5 * p1.y + h6 * p1.z + h7 * p1.w;
    #pragma unroll
    for (int o = 16; o; o >>= 1) p += __shfl_xor(p, o);
    if (lane == 0) {
        int b = node >> 12;
        int n = node & (N - 1);
        out[b * (3 * N) + sec * N + n] = p + pb[0];
    }
}

extern "C" void kernel_launch(void* const* d_in, const int* in_sizes, int n_in,
                              void* d_out, int out_size, void* d_ws, size_t ws_size,
                              hipStream_t stream) {
    const float* x   = (const float*)d_in[0];
    const int*   ei  = (const int*)d_in[1];
    const float* W1  = (const float*)d_in[2];
    const float* as1 = (const float*)d_in[3];
    const float* ad1 = (const float*)d_in[4];
    const float* b1  = (const float*)d_in[5];
    const float* W2  = (const float*)d_in[6];
    const float* as2 = (const float*)d_in[7];
    const float* ad2 = (const float*)d_in[8];
    const float* b2  = (const float*)d_in[9];
    const float* pw1 = (const float*)d_in[10];
    const float* pb1 = (const float*)d_in[11];
    const float* pw2 = (const float*)d_in[12];
    const float* pb2 = (const float*)d_in[13];
    float* out = (float*)d_out;

    // workspace layout (16B aligned blocks); xpb/asrc have +1 sentinel row
    unsigned short* xpb  = (unsigned short*)d_ws;             // (NT+1)*D1 bf16
    unsigned short* xhi  = xpb  + (size_t)(NT + 1) * D1;      // NT*FIN
    unsigned short* xlo  = xhi  + (size_t)NT * FIN;           // NT*FIN
    unsigned short* h1hi = xlo  + (size_t)NT * FIN;           // NT*D1
    unsigned short* h1lo = h1hi + (size_t)NT * D1;            // NT*D1
    float*    asrc   = (float*)(h1lo + (size_t)NT * D1);      // (NT+1)*H
    float*    adst   = asrc + (size_t)(NT + 1) * H;           // NT*H
    unsigned short* pB1 = (unsigned short*)(adst + (size_t)NT * H); // 4*18*64*8
    unsigned short* pB2 = pB1 + (size_t)4 * NSLOT * 64 * 8;         // 8*18*64*8
    unsigned* cnt    = (unsigned*)(pB2 + (size_t)8 * NSLOT * 64 * 8); // NT
    int*      slots  = (int*)(cnt + NT);                      // NT*CAP
    unsigned short* pos  = (unsigned short*)(slots + (size_t)NT * CAP); // E
    unsigned short* bcnt = pos + (size_t)E;                   // NT*8

    // 6 dispatches, zero global atomics
    k_combo<<<118 + NT / 8, 256, 0, stream>>>(x, ei, xhi, xlo, out, pos, bcnt,
                                              W1, as1, ad1, W2, as2, ad2, pB1, pB2,
                                              asrc, xpb);
    k_basepad<<<128, 256, 0, stream>>>(bcnt, cnt, slots);

    // ---------------- layer 1 (K = 128) + phase-C scatter ----------------
    k_mfma<128, true><<<NT / 64 + 512, 256, 0, stream>>>(
        xhi, xlo, pB1, xpb, asrc, adst, ei, pos, bcnt, slots);
    k_node<<<NT / 4, 256, 0, stream>>>(cnt, slots, asrc, adst, xpb,
                                       b1, pw1, pb1, h1hi, h1lo, out, 1);

    // ---------------- layer 2 (K = 256) ----------------
    k_mfma<256, false><<<NT / 64, 256, 0, stream>>>(
        h1hi, h1lo, pB2, xpb, asrc, adst, nullptr, nullptr, nullptr, nullptr);
    k_node<<<NT / 4, 256, 0, stream>>>(cnt, slots, asrc, adst, xpb,
                                       b2, pw2, pb2, nullptr, nullptr, out, 2);
}